// Round 1
// baseline (301.010 us; speedup 1.0000x reference)
//
#include <hip/hip_runtime.h>

#define HID 128

typedef __attribute__((ext_vector_type(8))) short short8;
typedef __attribute__((ext_vector_type(4))) float floatx4;

__device__ __forceinline__ float bflo(unsigned u){ return __uint_as_float(u << 16); }
__device__ __forceinline__ float bfhi(unsigned u){ return __uint_as_float(u & 0xffff0000u); }
__device__ __forceinline__ unsigned packbf2(float a, float b){
  unsigned ua = __float_as_uint(a), ub = __float_as_uint(b);
  ua = (ua + 0x7fffu + ((ua >> 16) & 1u)) >> 16;
  ub = (ub + 0x7fffu + ((ub >> 16) & 1u)) >> 16;
  return (ua & 0xffffu) | ((ub & 0xffffu) << 16);
}
__device__ __forceinline__ short8 as_s8(uint4 v){ short8 r; __builtin_memcpy(&r, &v, 16); return r; }

// ---- degree histogram ----
__global__ __launch_bounds__(256) void k_deg(const int* __restrict__ dst, int* __restrict__ cnt, int E){
  int e = blockIdx.x*256 + threadIdx.x;
  if (e < E) atomicAdd(&cnt[dst[e]], 1);
}

__global__ __launch_bounds__(256) void k_dinv(const int* __restrict__ cnt, float* __restrict__ dinv, int N){
  int n = blockIdx.x*256 + threadIdx.x;
  if (n < N) dinv[n] = 1.0f / sqrtf((float)cnt[n] + 1.0f);
}

// ---- hierarchical exclusive scan (CSR row_ptr) ----
__global__ __launch_bounds__(1024) void k_scan1(const int* __restrict__ cnt, int* __restrict__ rp,
                                                int* __restrict__ bsum, int N){
  __shared__ int s[1024];
  int t = threadIdx.x;
  int i = blockIdx.x*1024 + t;
  int v = (i < N) ? cnt[i] : 0;
  s[t] = v;
  __syncthreads();
  for (int d = 1; d < 1024; d <<= 1) {
    int add = (t >= d) ? s[t - d] : 0;
    __syncthreads();
    s[t] += add;
    __syncthreads();
  }
  if (i < N) rp[i] = s[t] - v;          // exclusive within chunk
  if (t == 1023) bsum[blockIdx.x] = s[1023];
}

__global__ void k_scan2(int* __restrict__ bsum, int* __restrict__ rp, int nb, int N){
  int run = 0;
  for (int b = 0; b < nb; ++b) { int x = bsum[b]; bsum[b] = run; run += x; }
  rp[N] = run;  // == E
}

__global__ __launch_bounds__(1024) void k_scan3(int* __restrict__ rp, int* __restrict__ cursor,
                                                const int* __restrict__ bsum, int N){
  int i = blockIdx.x*1024 + threadIdx.x;
  if (i < N) {
    int v = rp[i] + bsum[blockIdx.x];
    rp[i] = v;
    cursor[i] = v;
  }
}

// ---- CSR fill (by dst), store src index + dinv[src] weight ----
__global__ __launch_bounds__(256) void k_fill(const int* __restrict__ src, const int* __restrict__ dst,
                                              int* __restrict__ cursor, int* __restrict__ col,
                                              float* __restrict__ wgt, const float* __restrict__ dinv, int E){
  int e = blockIdx.x*256 + threadIdx.x;
  if (e < E){
    int d = dst[e], s = src[e];
    int pos = atomicAdd(&cursor[d], 1);
    col[pos] = s;
    wgt[pos] = dinv[s];
  }
}

// ---- W_convs -> bf16 MFMA A-fragment order: wf[l][(kt*8+ct)*64+lane] = 8 bf16 ----
// element i: W[l][kt*32+(lane>>4)*8+i][ct*16+(lane&15)]
__global__ __launch_bounds__(256) void k_prepw(const float* __restrict__ Wc, uint4* __restrict__ wf){
  int t = blockIdx.x*256 + threadIdx.x;
  if (t >= 3*2048) return;
  int l = t >> 11, r = t & 2047;
  int kt = r >> 9, ct = (r >> 6) & 7, lane = r & 63;
  int kbase = kt*32 + (lane >> 4)*8;
  int m = ct*16 + (lane & 15);
  const float* Wl = Wc + l*16384;
  float v[8];
  #pragma unroll
  for (int i = 0; i < 8; ++i) v[i] = Wl[(kbase + i)*128 + m];
  uint4 o;
  o.x = packbf2(v[0], v[1]);
  o.y = packbf2(v[2], v[3]);
  o.z = packbf2(v[4], v[5]);
  o.w = packbf2(v[6], v[7]);
  wf[t] = o;
}

// ---- h0 = relu(x*W_in + b_in), bf16 packed (2 cols per u32) ----
__global__ __launch_bounds__(256) void k_h0(const float* __restrict__ x, const float* __restrict__ Win,
                                            const float* __restrict__ bin, unsigned* __restrict__ h, int N){
  int idx = blockIdx.x*256 + threadIdx.x;
  if (idx >= N*64) return;
  int n = idx >> 6, j = idx & 63;
  float xv = x[n];
  int c0 = j*2;
  float a = fmaxf(fmaf(xv, Win[c0],   bin[c0]),   0.f);
  float b = fmaxf(fmaf(xv, Win[c0+1], bin[c0+1]), 0.f);
  h[idx] = packbf2(a, b);
}

// ---- hw = h @ W (bf16 MFMA). A=W fragment (from LDS), B=h rows. D: lane holds
// 4 consecutive channels of one node -> packed 8B stores. ----
__global__ __launch_bounds__(256) void k_gemm(const unsigned short* __restrict__ hin,
                                              const uint4* __restrict__ wf,
                                              unsigned short* __restrict__ hwout, int N){
  __shared__ uint4 lwf[2048];  // 32KB, full fragment-ordered W
  int t = threadIdx.x;
  #pragma unroll
  for (int j = 0; j < 8; ++j) lwf[t + j*256] = wf[t + j*256];
  __syncthreads();
  int lane = t & 63, w = t >> 6;
  int rb = blockIdx.x*64 + w*16;
  int nrow = rb + (lane & 15);
  int nclamp = nrow < N ? nrow : N - 1;
  const uint4* hp = (const uint4*)(hin + (size_t)nclamp*128 + (lane >> 4)*8);
  floatx4 acc[8];
  #pragma unroll
  for (int c = 0; c < 8; ++c) acc[c] = (floatx4){0.f,0.f,0.f,0.f};
  #pragma unroll
  for (int kt = 0; kt < 4; ++kt) {
    short8 hf = as_s8(hp[kt*4]);               // h[nrow][kt*32+(lane>>4)*8 .. +7]
    #pragma unroll
    for (int c = 0; c < 8; ++c) {
      short8 af = as_s8(lwf[(kt*8 + c)*64 + lane]);
      acc[c] = __builtin_amdgcn_mfma_f32_16x16x32_bf16(af, hf, acc[c], 0, 0, 0);
    }
  }
  if (nrow < N) {
    unsigned short* op = hwout + (size_t)nrow*128 + (lane >> 4)*4;
    #pragma unroll
    for (int c = 0; c < 8; ++c) {
      uint2 pk;
      pk.x = packbf2(acc[c][0], acc[c][1]);
      pk.y = packbf2(acc[c][2], acc[c][3]);
      *(uint2*)(op + c*16) = pk;
    }
  }
}

// ---- aggregation: h = relu(dinv[n]*(sum_e dinv[src]*hw[src] + dinv[n]*hw[n]) + b)
// one wave per node, 2 channels per lane ----
__global__ __launch_bounds__(256) void k_agg(const unsigned* __restrict__ hw, unsigned* __restrict__ h,
                                             const int* __restrict__ rp, const int* __restrict__ col,
                                             const float* __restrict__ wgt, const float* __restrict__ dinv,
                                             const float* __restrict__ bias, int N){
  int wid = (blockIdx.x * blockDim.x + threadIdx.x) >> 6;
  int lane = threadIdx.x & 63;
  if (wid >= N) return;
  float dn = dinv[wid];
  size_t base = (size_t)wid * 64;
  unsigned u = hw[base + lane];                 // self row
  float ax = dn * bflo(u), ay = dn * bfhi(u);
  int e0 = rp[wid], e1 = rp[wid + 1];
  int sn = 0; float wn = 0.f;
  if (e0 < e1) { sn = col[e0]; wn = wgt[e0]; }
  for (int e = e0; e < e1; ++e) {
    int s = sn; float wv = wn;
    if (e + 1 < e1) { sn = col[e + 1]; wn = wgt[e + 1]; }
    unsigned v = hw[(size_t)s*64 + lane];
    ax = fmaf(wv, bflo(v), ax);
    ay = fmaf(wv, bfhi(v), ay);
  }
  float bx = bias[lane*2], by = bias[lane*2 + 1];
  float rx = fmaxf(fmaf(dn, ax, bx), 0.f);
  float ry = fmaxf(fmaf(dn, ay, by), 0.f);
  h[base + lane] = packbf2(rx, ry);
}

// ---- global mean pool; batch is sorted -> binary search range per graph ----
__global__ __launch_bounds__(64) void k_pool(const unsigned* __restrict__ h, const int* __restrict__ batch,
                                             float* __restrict__ gp, int N, int G){
  int g = blockIdx.x, lane = threadIdx.x;
  int lo, hi;
  { int a = 0, b = N; while (a < b) { int m = (a + b) >> 1; if (batch[m] < g) a = m + 1; else b = m; } lo = a; }
  { int a = lo, b = N; while (a < b) { int m = (a + b) >> 1; if (batch[m] < g + 1) a = m + 1; else b = m; } hi = a; }
  float ax = 0.f, ay = 0.f;
  for (int n = lo; n < hi; ++n) {
    unsigned u = h[(size_t)n*64 + lane];
    ax += bflo(u); ay += bfhi(u);
  }
  float inv = 1.0f / fmaxf((float)(hi - lo), 1.0f);
  gp[g*128 + lane*2]     = ax * inv;
  gp[g*128 + lane*2 + 1] = ay * inv;
}

// ---- out = relu(g @ W_out + b_out), fp32 vector ----
__global__ __launch_bounds__(128) void k_out(const float* __restrict__ gp, const float* __restrict__ Wout,
                                             const float* __restrict__ bout, float* __restrict__ out, int G){
  __shared__ float sg[128];
  int g = blockIdx.x, c = threadIdx.x;
  sg[c] = gp[g*128 + c];
  __syncthreads();
  float a = 0.f;
  #pragma unroll
  for (int k = 0; k < 128; ++k) a = fmaf(sg[k], Wout[k*128 + c], a);
  out[g*128 + c] = fmaxf(a + bout[c], 0.f);
}

extern "C" void kernel_launch(void* const* d_in, const int* in_sizes, int n_in,
                              void* d_out, int out_size, void* d_ws, size_t ws_size,
                              hipStream_t stream){
  (void)n_in; (void)ws_size;
  const float* x       = (const float*)d_in[0];
  const int*   ei      = (const int*)d_in[1];
  const int*   batch   = (const int*)d_in[2];
  const float* W_in    = (const float*)d_in[4];
  const float* b_in    = (const float*)d_in[5];
  const float* W_convs = (const float*)d_in[6];
  const float* b_convs = (const float*)d_in[7];
  const float* W_out   = (const float*)d_in[8];
  const float* b_out   = (const float*)d_in[9];
  float* out = (float*)d_out;

  int N = in_sizes[0];        // 100000
  int E = in_sizes[1] / 2;    // 400000
  int G = out_size / HID;     // 2048

  // workspace carve-up (~57MB total)
  char* p = (char*)d_ws;
  auto alloc = [&](size_t bytes) -> char* {
    char* r = p; p += (bytes + 255) & ~(size_t)255; return r;
  };
  unsigned* h      = (unsigned*)alloc((size_t)N * 64 * 4);   // [N][128] bf16
  unsigned* hw     = (unsigned*)alloc((size_t)N * 64 * 4);   // [N][128] bf16
  uint4*    wf     = (uint4*)   alloc(3 * 2048 * 16);        // frag-ordered W
  float*    dinv   = (float*)   alloc((size_t)N * 4);
  int*      cnt    = (int*)     alloc((size_t)N * 4);
  int*      rp     = (int*)     alloc((size_t)(N + 1) * 4);
  int*      cursor = (int*)     alloc((size_t)(N + 1) * 4);
  int*      col    = (int*)     alloc((size_t)E * 4);
  float*    wgt    = (float*)   alloc((size_t)E * 4);
  float*    gp     = (float*)   alloc((size_t)G * HID * 4);
  int*      bsum   = (int*)     alloc(4096);

  const int* src  = ei;
  const int* dstp = ei + E;

  hipMemsetAsync(cnt, 0, (size_t)N * 4, stream);
  k_deg <<<(E + 255) / 256, 256, 0, stream>>>(dstp, cnt, E);
  k_dinv<<<(N + 255) / 256, 256, 0, stream>>>(cnt, dinv, N);
  int nb = (N + 1023) / 1024;
  k_scan1<<<nb, 1024, 0, stream>>>(cnt, rp, bsum, N);
  k_scan2<<<1, 1, 0, stream>>>(bsum, rp, nb, N);
  k_scan3<<<nb, 1024, 0, stream>>>(rp, cursor, bsum, N);
  k_fill<<<(E + 255) / 256, 256, 0, stream>>>(src, dstp, cursor, col, wgt, dinv, E);
  k_prepw<<<24, 256, 0, stream>>>(W_convs, wf);
  k_h0<<<(N * 64 + 255) / 256, 256, 0, stream>>>(x, W_in, b_in, h, N);

  for (int l = 0; l < 3; ++l) {
    k_gemm<<<(N + 63) / 64, 256, 0, stream>>>((const unsigned short*)h, wf + l * 2048,
                                              (unsigned short*)hw, N);
    k_agg <<<(N + 3) / 4, 256, 0, stream>>>(hw, h, rp, col, wgt, dinv, b_convs + l * HID, N);
  }

  k_pool<<<G, 64, 0, stream>>>(h, batch, gp, N, G);
  k_out <<<G, HID, 0, stream>>>(gp, W_out, b_out, out, G);
}

// Round 2
// 254.956 us; speedup vs baseline: 1.1806x; 1.1806x over previous
//
#include <hip/hip_runtime.h>

#define HID 128

typedef __attribute__((ext_vector_type(8))) short short8;
typedef __attribute__((ext_vector_type(4))) float floatx4;

__device__ __forceinline__ float bflo(unsigned u){ return __uint_as_float(u << 16); }
__device__ __forceinline__ float bfhi(unsigned u){ return __uint_as_float(u & 0xffff0000u); }
__device__ __forceinline__ unsigned packbf2(float a, float b){
  unsigned ua = __float_as_uint(a), ub = __float_as_uint(b);
  ua = (ua + 0x7fffu + ((ua >> 16) & 1u)) >> 16;
  ub = (ub + 0x7fffu + ((ub >> 16) & 1u)) >> 16;
  return (ua & 0xffffu) | ((ub & 0xffffu) << 16);
}
__device__ __forceinline__ short8 as_s8(uint4 v){ short8 r; __builtin_memcpy(&r, &v, 16); return r; }

// ---- degree histogram ----
__global__ __launch_bounds__(256) void k_deg(const int* __restrict__ dst, int* __restrict__ cnt, int E){
  int e = blockIdx.x*256 + threadIdx.x;
  if (e < E) atomicAdd(&cnt[dst[e]], 1);
}

__global__ __launch_bounds__(256) void k_dinv(const int* __restrict__ cnt, float* __restrict__ dinv, int N){
  int n = blockIdx.x*256 + threadIdx.x;
  if (n < N) dinv[n] = 1.0f / sqrtf((float)cnt[n] + 1.0f);
}

// ---- hierarchical exclusive scan (CSR row_ptr) ----
__global__ __launch_bounds__(1024) void k_scan1(const int* __restrict__ cnt, int* __restrict__ rp,
                                                int* __restrict__ bsum, int N){
  __shared__ int s[1024];
  int t = threadIdx.x;
  int i = blockIdx.x*1024 + t;
  int v = (i < N) ? cnt[i] : 0;
  s[t] = v;
  __syncthreads();
  for (int d = 1; d < 1024; d <<= 1) {
    int add = (t >= d) ? s[t - d] : 0;
    __syncthreads();
    s[t] += add;
    __syncthreads();
  }
  if (i < N) rp[i] = s[t] - v;          // exclusive within chunk
  if (t == 1023) bsum[blockIdx.x] = s[1023];
}

// parallel scan of block sums (nb <= 128)
__global__ __launch_bounds__(128) void k_scan2(int* __restrict__ bsum, int* __restrict__ rp, int nb, int N){
  __shared__ int s[128];
  int t = threadIdx.x;
  int v = (t < nb) ? bsum[t] : 0;
  s[t] = v;
  __syncthreads();
  for (int d = 1; d < 128; d <<= 1) {
    int add = (t >= d) ? s[t - d] : 0;
    __syncthreads();
    s[t] += add;
    __syncthreads();
  }
  if (t < nb) bsum[t] = s[t] - v;       // exclusive
  if (t == 127) rp[N] = s[127];         // == E
}

__global__ __launch_bounds__(1024) void k_scan3(int* __restrict__ rp, int* __restrict__ cursor,
                                                const int* __restrict__ bsum, int N){
  int i = blockIdx.x*1024 + threadIdx.x;
  if (i < N) {
    int v = rp[i] + bsum[blockIdx.x];
    rp[i] = v;
    cursor[i] = v;
  }
}

// ---- CSR fill (by dst): packed {src, dinv[src]} per edge ----
__global__ __launch_bounds__(256) void k_fill(const int* __restrict__ src, const int* __restrict__ dst,
                                              int* __restrict__ cursor, int2* __restrict__ ew,
                                              const float* __restrict__ dinv, int E){
  int e = blockIdx.x*256 + threadIdx.x;
  if (e < E){
    int d = dst[e], s = src[e];
    int pos = atomicAdd(&cursor[d], 1);
    int2 pk; pk.x = s; pk.y = __float_as_int(dinv[s]);
    ew[pos] = pk;
  }
}

// ---- W_convs -> bf16 MFMA A-fragment order: wf[l][(kt*8+ct)*64+lane] = 8 bf16 ----
// element i: W[l][kt*32+(lane>>4)*8+i][ct*16+(lane&15)]
__global__ __launch_bounds__(256) void k_prepw(const float* __restrict__ Wc, uint4* __restrict__ wf){
  int t = blockIdx.x*256 + threadIdx.x;
  if (t >= 3*2048) return;
  int l = t >> 11, r = t & 2047;
  int kt = r >> 9, ct = (r >> 6) & 7, lane = r & 63;
  int kbase = kt*32 + (lane >> 4)*8;
  int m = ct*16 + (lane & 15);
  const float* Wl = Wc + l*16384;
  float v[8];
  #pragma unroll
  for (int i = 0; i < 8; ++i) v[i] = Wl[(kbase + i)*128 + m];
  uint4 o;
  o.x = packbf2(v[0], v[1]);
  o.y = packbf2(v[2], v[3]);
  o.z = packbf2(v[4], v[5]);
  o.w = packbf2(v[6], v[7]);
  wf[t] = o;
}

// ---- layer-0 GEMM with fused h0 = relu(x*W_in + b_in) (rank-1, computed on the fly) ----
// 2 row-tiles (32 rows) per wave, 128 rows per block.
__global__ __launch_bounds__(256) void k_gemm0(const float* __restrict__ x,
                                               const float* __restrict__ Win,
                                               const float* __restrict__ bin,
                                               const uint4* __restrict__ wf,
                                               unsigned short* __restrict__ hwout, int N){
  __shared__ uint4 lwf[2048];  // 32KB fragment-ordered W
  __shared__ float sw[128], sb[128];
  int t = threadIdx.x;
  #pragma unroll
  for (int j = 0; j < 8; ++j) lwf[t + j*256] = wf[t + j*256];
  if (t < 128) { sw[t] = Win[t]; sb[t] = bin[t]; }
  __syncthreads();
  int lane = t & 63, w = t >> 6;
  int rb = blockIdx.x*128 + w*32;
  int nrow0 = rb + (lane & 15);
  int nrow1 = nrow0 + 16;
  float xv0 = x[nrow0 < N ? nrow0 : N - 1];
  float xv1 = x[nrow1 < N ? nrow1 : N - 1];
  floatx4 acc0[8], acc1[8];
  #pragma unroll
  for (int c = 0; c < 8; ++c) { acc0[c] = (floatx4){0.f,0.f,0.f,0.f}; acc1[c] = (floatx4){0.f,0.f,0.f,0.f}; }
  #pragma unroll
  for (int kt = 0; kt < 4; ++kt) {
    int k0 = kt*32 + (lane >> 4)*8;
    float hv0[8], hv1[8];
    #pragma unroll
    for (int i = 0; i < 8; ++i) {
      float wv = sw[k0 + i], bv = sb[k0 + i];
      hv0[i] = fmaxf(fmaf(xv0, wv, bv), 0.f);
      hv1[i] = fmaxf(fmaf(xv1, wv, bv), 0.f);
    }
    uint4 p0, p1;
    p0.x = packbf2(hv0[0], hv0[1]); p0.y = packbf2(hv0[2], hv0[3]);
    p0.z = packbf2(hv0[4], hv0[5]); p0.w = packbf2(hv0[6], hv0[7]);
    p1.x = packbf2(hv1[0], hv1[1]); p1.y = packbf2(hv1[2], hv1[3]);
    p1.z = packbf2(hv1[4], hv1[5]); p1.w = packbf2(hv1[6], hv1[7]);
    short8 hf0 = as_s8(p0), hf1 = as_s8(p1);
    #pragma unroll
    for (int c = 0; c < 8; ++c) {
      short8 af = as_s8(lwf[(kt*8 + c)*64 + lane]);
      acc0[c] = __builtin_amdgcn_mfma_f32_16x16x32_bf16(af, hf0, acc0[c], 0, 0, 0);
      acc1[c] = __builtin_amdgcn_mfma_f32_16x16x32_bf16(af, hf1, acc1[c], 0, 0, 0);
    }
  }
  if (nrow0 < N) {
    unsigned short* op = hwout + (size_t)nrow0*128 + (lane >> 4)*4;
    #pragma unroll
    for (int c = 0; c < 8; ++c) {
      uint2 pk;
      pk.x = packbf2(acc0[c][0], acc0[c][1]);
      pk.y = packbf2(acc0[c][2], acc0[c][3]);
      *(uint2*)(op + c*16) = pk;
    }
  }
  if (nrow1 < N) {
    unsigned short* op = hwout + (size_t)nrow1*128 + (lane >> 4)*4;
    #pragma unroll
    for (int c = 0; c < 8; ++c) {
      uint2 pk;
      pk.x = packbf2(acc1[c][0], acc1[c][1]);
      pk.y = packbf2(acc1[c][2], acc1[c][3]);
      *(uint2*)(op + c*16) = pk;
    }
  }
}

// ---- hw = h @ W (bf16 MFMA), 2 row-tiles per wave ----
__global__ __launch_bounds__(256) void k_gemm(const unsigned short* __restrict__ hin,
                                              const uint4* __restrict__ wf,
                                              unsigned short* __restrict__ hwout, int N){
  __shared__ uint4 lwf[2048];  // 32KB
  int t = threadIdx.x;
  #pragma unroll
  for (int j = 0; j < 8; ++j) lwf[t + j*256] = wf[t + j*256];
  __syncthreads();
  int lane = t & 63, w = t >> 6;
  int rb = blockIdx.x*128 + w*32;
  int nrow0 = rb + (lane & 15);
  int nrow1 = nrow0 + 16;
  int nc0 = nrow0 < N ? nrow0 : N - 1;
  int nc1 = nrow1 < N ? nrow1 : N - 1;
  const uint4* hp0 = (const uint4*)(hin + (size_t)nc0*128 + (lane >> 4)*8);
  const uint4* hp1 = (const uint4*)(hin + (size_t)nc1*128 + (lane >> 4)*8);
  floatx4 acc0[8], acc1[8];
  #pragma unroll
  for (int c = 0; c < 8; ++c) { acc0[c] = (floatx4){0.f,0.f,0.f,0.f}; acc1[c] = (floatx4){0.f,0.f,0.f,0.f}; }
  #pragma unroll
  for (int kt = 0; kt < 4; ++kt) {
    short8 hf0 = as_s8(hp0[kt*4]);
    short8 hf1 = as_s8(hp1[kt*4]);
    #pragma unroll
    for (int c = 0; c < 8; ++c) {
      short8 af = as_s8(lwf[(kt*8 + c)*64 + lane]);
      acc0[c] = __builtin_amdgcn_mfma_f32_16x16x32_bf16(af, hf0, acc0[c], 0, 0, 0);
      acc1[c] = __builtin_amdgcn_mfma_f32_16x16x32_bf16(af, hf1, acc1[c], 0, 0, 0);
    }
  }
  if (nrow0 < N) {
    unsigned short* op = hwout + (size_t)nrow0*128 + (lane >> 4)*4;
    #pragma unroll
    for (int c = 0; c < 8; ++c) {
      uint2 pk;
      pk.x = packbf2(acc0[c][0], acc0[c][1]);
      pk.y = packbf2(acc0[c][2], acc0[c][3]);
      *(uint2*)(op + c*16) = pk;
    }
  }
  if (nrow1 < N) {
    unsigned short* op = hwout + (size_t)nrow1*128 + (lane >> 4)*4;
    #pragma unroll
    for (int c = 0; c < 8; ++c) {
      uint2 pk;
      pk.x = packbf2(acc1[c][0], acc1[c][1]);
      pk.y = packbf2(acc1[c][2], acc1[c][3]);
      *(uint2*)(op + c*16) = pk;
    }
  }
}

// ---- aggregation: h = relu(dinv[n]*(sum_e dinv[src]*hw[src] + dinv[n]*hw[n]) + b)
// one wave per node, 2 channels per lane, edge loop unrolled x4 for MLP ----
__global__ __launch_bounds__(256) void k_agg(const unsigned* __restrict__ hw, unsigned* __restrict__ h,
                                             const int* __restrict__ rp, const int2* __restrict__ ew,
                                             const float* __restrict__ dinv,
                                             const float* __restrict__ bias, int N){
  int wid = (blockIdx.x * blockDim.x + threadIdx.x) >> 6;
  int lane = threadIdx.x & 63;
  if (wid >= N) return;
  float dn = dinv[wid];
  size_t base = (size_t)wid * 64;
  unsigned u = hw[base + lane];                 // self row
  float ax0 = dn * bflo(u), ay0 = dn * bfhi(u);
  float ax1 = 0.f, ay1 = 0.f, ax2 = 0.f, ay2 = 0.f, ax3 = 0.f, ay3 = 0.f;
  int e0 = rp[wid], e1 = rp[wid + 1];
  int e = e0;
  for (; e + 4 <= e1; e += 4) {
    int2 p0 = ew[e], p1 = ew[e+1], p2 = ew[e+2], p3 = ew[e+3];
    unsigned v0 = hw[(size_t)p0.x * 64 + lane];
    unsigned v1 = hw[(size_t)p1.x * 64 + lane];
    unsigned v2 = hw[(size_t)p2.x * 64 + lane];
    unsigned v3 = hw[(size_t)p3.x * 64 + lane];
    float w0 = __int_as_float(p0.y), w1 = __int_as_float(p1.y);
    float w2 = __int_as_float(p2.y), w3 = __int_as_float(p3.y);
    ax0 = fmaf(w0, bflo(v0), ax0); ay0 = fmaf(w0, bfhi(v0), ay0);
    ax1 = fmaf(w1, bflo(v1), ax1); ay1 = fmaf(w1, bfhi(v1), ay1);
    ax2 = fmaf(w2, bflo(v2), ax2); ay2 = fmaf(w2, bfhi(v2), ay2);
    ax3 = fmaf(w3, bflo(v3), ax3); ay3 = fmaf(w3, bfhi(v3), ay3);
  }
  for (; e < e1; ++e) {
    int2 p = ew[e];
    unsigned v = hw[(size_t)p.x * 64 + lane];
    float wv = __int_as_float(p.y);
    ax0 = fmaf(wv, bflo(v), ax0); ay0 = fmaf(wv, bfhi(v), ay0);
  }
  float ax = (ax0 + ax1) + (ax2 + ax3);
  float ay = (ay0 + ay1) + (ay2 + ay3);
  float bx = bias[lane*2], by = bias[lane*2 + 1];
  float rx = fmaxf(fmaf(dn, ax, bx), 0.f);
  float ry = fmaxf(fmaf(dn, ay, by), 0.f);
  h[base + lane] = packbf2(rx, ry);
}

// ---- global mean pool; batch sorted -> binary search range per graph.
// 4 graphs/block, one wave per graph; wave streams 4 rows (1KB) per iter. ----
__global__ __launch_bounds__(256) void k_pool(const uint4* __restrict__ h4, const int* __restrict__ batch,
                                              float* __restrict__ gp, int N, int G){
  int g = blockIdx.x * 4 + (threadIdx.x >> 6);
  int lane = threadIdx.x & 63;
  if (g >= G) return;
  int lo, hi;
  { int a = 0, b = N; while (a < b) { int m = (a + b) >> 1; if (batch[m] < g) a = m + 1; else b = m; } lo = a; }
  { int a = lo, b = N; while (a < b) { int m = (a + b) >> 1; if (batch[m] < g + 1) a = m + 1; else b = m; } hi = a; }
  int r = lane >> 4;        // row offset within 4-row chunk
  int c = lane & 15;        // 16B chunk within row (8 channels)
  float a0=0.f,a1=0.f,a2=0.f,a3=0.f,a4=0.f,a5=0.f,a6=0.f,a7=0.f;
  for (int n = lo + r; n < hi; n += 4) {
    uint4 v = h4[(size_t)n*16 + c];
    a0 += bflo(v.x); a1 += bfhi(v.x);
    a2 += bflo(v.y); a3 += bfhi(v.y);
    a4 += bflo(v.z); a5 += bfhi(v.z);
    a6 += bflo(v.w); a7 += bfhi(v.w);
  }
  #pragma unroll
  for (int m = 16; m <= 32; m <<= 1) {
    a0 += __shfl_xor(a0, m, 64); a1 += __shfl_xor(a1, m, 64);
    a2 += __shfl_xor(a2, m, 64); a3 += __shfl_xor(a3, m, 64);
    a4 += __shfl_xor(a4, m, 64); a5 += __shfl_xor(a5, m, 64);
    a6 += __shfl_xor(a6, m, 64); a7 += __shfl_xor(a7, m, 64);
  }
  if (r == 0) {
    float inv = 1.0f / fmaxf((float)(hi - lo), 1.0f);
    float4* o = (float4*)(gp + (size_t)g*128 + c*8);
    o[0] = (float4){a0*inv, a1*inv, a2*inv, a3*inv};
    o[1] = (float4){a4*inv, a5*inv, a6*inv, a7*inv};
  }
}

// ---- out = relu(g @ W_out + b_out), fp32 vector ----
__global__ __launch_bounds__(128) void k_out(const float* __restrict__ gp, const float* __restrict__ Wout,
                                             const float* __restrict__ bout, float* __restrict__ out, int G){
  __shared__ float sg[128];
  int g = blockIdx.x, c = threadIdx.x;
  sg[c] = gp[g*128 + c];
  __syncthreads();
  float a = 0.f;
  #pragma unroll
  for (int k = 0; k < 128; ++k) a = fmaf(sg[k], Wout[k*128 + c], a);
  out[g*128 + c] = fmaxf(a + bout[c], 0.f);
}

extern "C" void kernel_launch(void* const* d_in, const int* in_sizes, int n_in,
                              void* d_out, int out_size, void* d_ws, size_t ws_size,
                              hipStream_t stream){
  (void)n_in; (void)ws_size;
  const float* x       = (const float*)d_in[0];
  const int*   ei      = (const int*)d_in[1];
  const int*   batch   = (const int*)d_in[2];
  const float* W_in    = (const float*)d_in[4];
  const float* b_in    = (const float*)d_in[5];
  const float* W_convs = (const float*)d_in[6];
  const float* b_convs = (const float*)d_in[7];
  const float* W_out   = (const float*)d_in[8];
  const float* b_out   = (const float*)d_in[9];
  float* out = (float*)d_out;

  int N = in_sizes[0];        // 100000
  int E = in_sizes[1] / 2;    // 400000
  int G = out_size / HID;     // 2048

  char* p = (char*)d_ws;
  auto alloc = [&](size_t bytes) -> char* {
    char* r = p; p += (bytes + 255) & ~(size_t)255; return r;
  };
  unsigned* h      = (unsigned*)alloc((size_t)N * 64 * 4);   // [N][128] bf16
  unsigned* hw     = (unsigned*)alloc((size_t)N * 64 * 4);   // [N][128] bf16
  uint4*    wf     = (uint4*)   alloc(3 * 2048 * 16);        // frag-ordered W
  float*    dinv   = (float*)   alloc((size_t)N * 4);
  int*      cnt    = (int*)     alloc((size_t)N * 4);
  int*      rp     = (int*)     alloc((size_t)(N + 1) * 4);
  int*      cursor = (int*)     alloc((size_t)(N + 1) * 4);
  int2*     ew     = (int2*)    alloc((size_t)E * 8);        // {src, dinv[src]}
  float*    gp     = (float*)   alloc((size_t)G * HID * 4);
  int*      bsum   = (int*)     alloc(4096);

  const int* src  = ei;
  const int* dstp = ei + E;

  hipMemsetAsync(cnt, 0, (size_t)N * 4, stream);
  k_deg <<<(E + 255) / 256, 256, 0, stream>>>(dstp, cnt, E);
  k_dinv<<<(N + 255) / 256, 256, 0, stream>>>(cnt, dinv, N);
  int nb = (N + 1023) / 1024;
  k_scan1<<<nb, 1024, 0, stream>>>(cnt, rp, bsum, N);
  k_scan2<<<1, 128, 0, stream>>>(bsum, rp, nb, N);
  k_scan3<<<nb, 1024, 0, stream>>>(rp, cursor, bsum, N);
  k_fill<<<(E + 255) / 256, 256, 0, stream>>>(src, dstp, cursor, ew, dinv, E);
  k_prepw<<<24, 256, 0, stream>>>(W_convs, wf);

  int gb = (N + 127) / 128;
  k_gemm0<<<gb, 256, 0, stream>>>(x, W_in, b_in, wf, (unsigned short*)hw, N);
  k_agg  <<<(N + 3) / 4, 256, 0, stream>>>(hw, h, rp, ew, dinv, b_convs, N);
  for (int l = 1; l < 3; ++l) {
    k_gemm<<<gb, 256, 0, stream>>>((const unsigned short*)h, wf + l * 2048,
                                   (unsigned short*)hw, N);
    k_agg <<<(N + 3) / 4, 256, 0, stream>>>(hw, h, rp, ew, dinv, b_convs + l * HID, N);
  }

  k_pool<<<(G + 3) / 4, 256, 0, stream>>>((const uint4*)h, batch, gp, N, G);
  k_out <<<G, HID, 0, stream>>>(gp, W_out, b_out, out, G);
}

// Round 3
// 242.581 us; speedup vs baseline: 1.2409x; 1.0510x over previous
//
#include <hip/hip_runtime.h>

#define HID 128

typedef __attribute__((ext_vector_type(8))) short short8;
typedef __attribute__((ext_vector_type(4))) float floatx4;

__device__ __forceinline__ float bflo(unsigned u){ return __uint_as_float(u << 16); }
__device__ __forceinline__ float bfhi(unsigned u){ return __uint_as_float(u & 0xffff0000u); }
__device__ __forceinline__ unsigned packbf2(float a, float b){
  unsigned ua = __float_as_uint(a), ub = __float_as_uint(b);
  ua = (ua + 0x7fffu + ((ua >> 16) & 1u)) >> 16;
  ub = (ub + 0x7fffu + ((ub >> 16) & 1u)) >> 16;
  return (ua & 0xffffu) | ((ub & 0xffffu) << 16);
}
__device__ __forceinline__ short8 as_s8(uint4 v){ short8 r; __builtin_memcpy(&r, &v, 16); return r; }

// ---- zero cnt (custom: rocclr fillBuffer took 45us in-graph) ----
__global__ __launch_bounds__(256) void k_zero(int* __restrict__ p, int n){
  int i = blockIdx.x*256 + threadIdx.x;
  int n4 = n >> 2;
  if (i < n4) ((int4*)p)[i] = (int4){0,0,0,0};
  if (i == 0) for (int r = n4*4; r < n; ++r) p[r] = 0;
}

// ---- degree histogram ----
__global__ __launch_bounds__(256) void k_deg(const int* __restrict__ dst, int* __restrict__ cnt, int E){
  int e = blockIdx.x*256 + threadIdx.x;
  if (e < E) atomicAdd(&cnt[dst[e]], 1);
}

// ---- hierarchical exclusive scan (CSR row_ptr) + dinv ----
__global__ __launch_bounds__(1024) void k_scan1(const int* __restrict__ cnt, int* __restrict__ rp,
                                                int* __restrict__ bsum, float* __restrict__ dinv, int N){
  __shared__ int s[1024];
  int t = threadIdx.x;
  int i = blockIdx.x*1024 + t;
  int v = (i < N) ? cnt[i] : 0;
  s[t] = v;
  __syncthreads();
  for (int d = 1; d < 1024; d <<= 1) {
    int add = (t >= d) ? s[t - d] : 0;
    __syncthreads();
    s[t] += add;
    __syncthreads();
  }
  if (i < N) {
    rp[i] = s[t] - v;          // exclusive within chunk
    dinv[i] = 1.0f / sqrtf((float)v + 1.0f);
  }
  if (t == 1023) bsum[blockIdx.x] = s[1023];
}

// parallel scan of block sums (nb <= 128)
__global__ __launch_bounds__(128) void k_scan2(int* __restrict__ bsum, int* __restrict__ rp, int nb, int N){
  __shared__ int s[128];
  int t = threadIdx.x;
  int v = (t < nb) ? bsum[t] : 0;
  s[t] = v;
  __syncthreads();
  for (int d = 1; d < 128; d <<= 1) {
    int add = (t >= d) ? s[t - d] : 0;
    __syncthreads();
    s[t] += add;
    __syncthreads();
  }
  if (t < nb) bsum[t] = s[t] - v;       // exclusive
  if (t == 127) rp[N] = s[127];         // == E
}

__global__ __launch_bounds__(1024) void k_scan3(int* __restrict__ rp, int* __restrict__ cursor,
                                                const int* __restrict__ bsum, int N){
  int i = blockIdx.x*1024 + threadIdx.x;
  if (i < N) {
    int v = rp[i] + bsum[blockIdx.x];
    rp[i] = v;
    cursor[i] = v;
  }
}

// ---- CSR fill (by dst): packed {src, dinv[src]} per edge ----
__global__ __launch_bounds__(256) void k_fill(const int* __restrict__ src, const int* __restrict__ dst,
                                              int* __restrict__ cursor, int2* __restrict__ ew,
                                              const float* __restrict__ dinv, int E){
  int e = blockIdx.x*256 + threadIdx.x;
  if (e < E){
    int d = dst[e], s = src[e];
    int pos = atomicAdd(&cursor[d], 1);
    int2 pk; pk.x = s; pk.y = __float_as_int(dinv[s]);
    ew[pos] = pk;
  }
}

// ---- W_convs -> bf16 MFMA A-fragment order: wf[l][(kt*8+ct)*64+lane] = 8 bf16 ----
__global__ __launch_bounds__(256) void k_prepw(const float* __restrict__ Wc, uint4* __restrict__ wf){
  int t = blockIdx.x*256 + threadIdx.x;
  if (t >= 3*2048) return;
  int l = t >> 11, r = t & 2047;
  int kt = r >> 9, ct = (r >> 6) & 7, lane = r & 63;
  int kbase = kt*32 + (lane >> 4)*8;
  int m = ct*16 + (lane & 15);
  const float* Wl = Wc + l*16384;
  float v[8];
  #pragma unroll
  for (int i = 0; i < 8; ++i) v[i] = Wl[(kbase + i)*128 + m];
  uint4 o;
  o.x = packbf2(v[0], v[1]);
  o.y = packbf2(v[2], v[3]);
  o.z = packbf2(v[4], v[5]);
  o.w = packbf2(v[6], v[7]);
  wf[t] = o;
}

// ---- layer-0 GEMM with fused h0 = relu(x*W_in + b_in) ----
__global__ __launch_bounds__(256) void k_gemm0(const float* __restrict__ x,
                                               const float* __restrict__ Win,
                                               const float* __restrict__ bin,
                                               const uint4* __restrict__ wf,
                                               unsigned short* __restrict__ hwout, int N){
  __shared__ uint4 lwf[2048];
  __shared__ float sw[128], sb[128];
  int t = threadIdx.x;
  #pragma unroll
  for (int j = 0; j < 8; ++j) lwf[t + j*256] = wf[t + j*256];
  if (t < 128) { sw[t] = Win[t]; sb[t] = bin[t]; }
  __syncthreads();
  int lane = t & 63, w = t >> 6;
  int rb = blockIdx.x*128 + w*32;
  int nrow0 = rb + (lane & 15);
  int nrow1 = nrow0 + 16;
  float xv0 = x[nrow0 < N ? nrow0 : N - 1];
  float xv1 = x[nrow1 < N ? nrow1 : N - 1];
  floatx4 acc0[8], acc1[8];
  #pragma unroll
  for (int c = 0; c < 8; ++c) { acc0[c] = (floatx4){0.f,0.f,0.f,0.f}; acc1[c] = (floatx4){0.f,0.f,0.f,0.f}; }
  #pragma unroll
  for (int kt = 0; kt < 4; ++kt) {
    int k0 = kt*32 + (lane >> 4)*8;
    float hv0[8], hv1[8];
    #pragma unroll
    for (int i = 0; i < 8; ++i) {
      float wv = sw[k0 + i], bv = sb[k0 + i];
      hv0[i] = fmaxf(fmaf(xv0, wv, bv), 0.f);
      hv1[i] = fmaxf(fmaf(xv1, wv, bv), 0.f);
    }
    uint4 p0, p1;
    p0.x = packbf2(hv0[0], hv0[1]); p0.y = packbf2(hv0[2], hv0[3]);
    p0.z = packbf2(hv0[4], hv0[5]); p0.w = packbf2(hv0[6], hv0[7]);
    p1.x = packbf2(hv1[0], hv1[1]); p1.y = packbf2(hv1[2], hv1[3]);
    p1.z = packbf2(hv1[4], hv1[5]); p1.w = packbf2(hv1[6], hv1[7]);
    short8 hf0 = as_s8(p0), hf1 = as_s8(p1);
    #pragma unroll
    for (int c = 0; c < 8; ++c) {
      short8 af = as_s8(lwf[(kt*8 + c)*64 + lane]);
      acc0[c] = __builtin_amdgcn_mfma_f32_16x16x32_bf16(af, hf0, acc0[c], 0, 0, 0);
      acc1[c] = __builtin_amdgcn_mfma_f32_16x16x32_bf16(af, hf1, acc1[c], 0, 0, 0);
    }
  }
  if (nrow0 < N) {
    unsigned short* op = hwout + (size_t)nrow0*128 + (lane >> 4)*4;
    #pragma unroll
    for (int c = 0; c < 8; ++c) {
      uint2 pk;
      pk.x = packbf2(acc0[c][0], acc0[c][1]);
      pk.y = packbf2(acc0[c][2], acc0[c][3]);
      *(uint2*)(op + c*16) = pk;
    }
  }
  if (nrow1 < N) {
    unsigned short* op = hwout + (size_t)nrow1*128 + (lane >> 4)*4;
    #pragma unroll
    for (int c = 0; c < 8; ++c) {
      uint2 pk;
      pk.x = packbf2(acc1[c][0], acc1[c][1]);
      pk.y = packbf2(acc1[c][2], acc1[c][3]);
      *(uint2*)(op + c*16) = pk;
    }
  }
}

// ---- hw = h @ W (bf16 MFMA), 2 row-tiles per wave ----
__global__ __launch_bounds__(256) void k_gemm(const unsigned short* __restrict__ hin,
                                              const uint4* __restrict__ wf,
                                              unsigned short* __restrict__ hwout, int N){
  __shared__ uint4 lwf[2048];
  int t = threadIdx.x;
  #pragma unroll
  for (int j = 0; j < 8; ++j) lwf[t + j*256] = wf[t + j*256];
  __syncthreads();
  int lane = t & 63, w = t >> 6;
  int rb = blockIdx.x*128 + w*32;
  int nrow0 = rb + (lane & 15);
  int nrow1 = nrow0 + 16;
  int nc0 = nrow0 < N ? nrow0 : N - 1;
  int nc1 = nrow1 < N ? nrow1 : N - 1;
  const uint4* hp0 = (const uint4*)(hin + (size_t)nc0*128 + (lane >> 4)*8);
  const uint4* hp1 = (const uint4*)(hin + (size_t)nc1*128 + (lane >> 4)*8);
  floatx4 acc0[8], acc1[8];
  #pragma unroll
  for (int c = 0; c < 8; ++c) { acc0[c] = (floatx4){0.f,0.f,0.f,0.f}; acc1[c] = (floatx4){0.f,0.f,0.f,0.f}; }
  #pragma unroll
  for (int kt = 0; kt < 4; ++kt) {
    short8 hf0 = as_s8(hp0[kt*4]);
    short8 hf1 = as_s8(hp1[kt*4]);
    #pragma unroll
    for (int c = 0; c < 8; ++c) {
      short8 af = as_s8(lwf[(kt*8 + c)*64 + lane]);
      acc0[c] = __builtin_amdgcn_mfma_f32_16x16x32_bf16(af, hf0, acc0[c], 0, 0, 0);
      acc1[c] = __builtin_amdgcn_mfma_f32_16x16x32_bf16(af, hf1, acc1[c], 0, 0, 0);
    }
  }
  if (nrow0 < N) {
    unsigned short* op = hwout + (size_t)nrow0*128 + (lane >> 4)*4;
    #pragma unroll
    for (int c = 0; c < 8; ++c) {
      uint2 pk;
      pk.x = packbf2(acc0[c][0], acc0[c][1]);
      pk.y = packbf2(acc0[c][2], acc0[c][3]);
      *(uint2*)(op + c*16) = pk;
    }
  }
  if (nrow1 < N) {
    unsigned short* op = hwout + (size_t)nrow1*128 + (lane >> 4)*4;
    #pragma unroll
    for (int c = 0; c < 8; ++c) {
      uint2 pk;
      pk.x = packbf2(acc1[c][0], acc1[c][1]);
      pk.y = packbf2(acc1[c][2], acc1[c][3]);
      *(uint2*)(op + c*16) = pk;
    }
  }
}

// ---- aggregation: one wave per node, uint2 (4ch) per lane, wave-halves
// process interleaved edges (8 edges / loop body, 4 gathers in flight/half) ----
__global__ __launch_bounds__(256) void k_agg(const uint2* __restrict__ hw2, uint2* __restrict__ h2,
                                             const int* __restrict__ rp, const int2* __restrict__ ew,
                                             const float* __restrict__ dinv,
                                             const float* __restrict__ bias, int N){
  int wid = (blockIdx.x * blockDim.x + threadIdx.x) >> 6;
  int lane = threadIdx.x & 63;
  if (wid >= N) return;
  int half = lane >> 5, c = lane & 31;
  float dn = dinv[wid];
  size_t rbase = (size_t)wid * 32;
  uint2 su = hw2[rbase + c];                       // self row slice
  float sw = half ? 0.f : dn;
  float a0 = sw * bflo(su.x), a1 = sw * bfhi(su.x);
  float a2 = sw * bflo(su.y), a3 = sw * bfhi(su.y);
  int e0 = rp[wid], e1 = rp[wid + 1];
  for (int eb = e0; eb < e1; eb += 8) {
    int i0 = eb + half;     // this half's edges: i0, i0+2, i0+4, i0+6
    int last = e1 - 1;
    int2 p0 = ew[i0     <= last ? i0     : last];
    int2 p1 = ew[i0 + 2 <= last ? i0 + 2 : last];
    int2 p2 = ew[i0 + 4 <= last ? i0 + 4 : last];
    int2 p3 = ew[i0 + 6 <= last ? i0 + 6 : last];
    float w0 = (i0     < e1) ? __int_as_float(p0.y) : 0.f;
    float w1 = (i0 + 2 < e1) ? __int_as_float(p1.y) : 0.f;
    float w2 = (i0 + 4 < e1) ? __int_as_float(p2.y) : 0.f;
    float w3 = (i0 + 6 < e1) ? __int_as_float(p3.y) : 0.f;
    uint2 v0 = hw2[(size_t)p0.x * 32 + c];
    uint2 v1 = hw2[(size_t)p1.x * 32 + c];
    uint2 v2 = hw2[(size_t)p2.x * 32 + c];
    uint2 v3 = hw2[(size_t)p3.x * 32 + c];
    a0 = fmaf(w0, bflo(v0.x), a0); a1 = fmaf(w0, bfhi(v0.x), a1);
    a2 = fmaf(w0, bflo(v0.y), a2); a3 = fmaf(w0, bfhi(v0.y), a3);
    a0 = fmaf(w1, bflo(v1.x), a0); a1 = fmaf(w1, bfhi(v1.x), a1);
    a2 = fmaf(w1, bflo(v1.y), a2); a3 = fmaf(w1, bfhi(v1.y), a3);
    a0 = fmaf(w2, bflo(v2.x), a0); a1 = fmaf(w2, bfhi(v2.x), a1);
    a2 = fmaf(w2, bflo(v2.y), a2); a3 = fmaf(w2, bfhi(v2.y), a3);
    a0 = fmaf(w3, bflo(v3.x), a0); a1 = fmaf(w3, bfhi(v3.x), a1);
    a2 = fmaf(w3, bflo(v3.y), a2); a3 = fmaf(w3, bfhi(v3.y), a3);
  }
  a0 += __shfl_xor(a0, 32, 64);
  a1 += __shfl_xor(a1, 32, 64);
  a2 += __shfl_xor(a2, 32, 64);
  a3 += __shfl_xor(a3, 32, 64);
  float4 bv = *(const float4*)(bias + c*4);
  float r0 = fmaxf(fmaf(dn, a0, bv.x), 0.f);
  float r1 = fmaxf(fmaf(dn, a1, bv.y), 0.f);
  float r2 = fmaxf(fmaf(dn, a2, bv.z), 0.f);
  float r3 = fmaxf(fmaf(dn, a3, bv.w), 0.f);
  if (!half) {
    uint2 o;
    o.x = packbf2(r0, r1);
    o.y = packbf2(r2, r3);
    h2[rbase + c] = o;
  }
}

// ---- global mean pool; 4 graphs/block, one wave per graph ----
__global__ __launch_bounds__(256) void k_pool(const uint4* __restrict__ h4, const int* __restrict__ batch,
                                              float* __restrict__ gp, int N, int G){
  int g = blockIdx.x * 4 + (threadIdx.x >> 6);
  int lane = threadIdx.x & 63;
  if (g >= G) return;
  int lo, hi;
  { int a = 0, b = N; while (a < b) { int m = (a + b) >> 1; if (batch[m] < g) a = m + 1; else b = m; } lo = a; }
  { int a = lo, b = N; while (a < b) { int m = (a + b) >> 1; if (batch[m] < g + 1) a = m + 1; else b = m; } hi = a; }
  int r = lane >> 4;
  int c = lane & 15;
  float a0=0.f,a1=0.f,a2=0.f,a3=0.f,a4=0.f,a5=0.f,a6=0.f,a7=0.f;
  for (int n = lo + r; n < hi; n += 4) {
    uint4 v = h4[(size_t)n*16 + c];
    a0 += bflo(v.x); a1 += bfhi(v.x);
    a2 += bflo(v.y); a3 += bfhi(v.y);
    a4 += bflo(v.z); a5 += bfhi(v.z);
    a6 += bflo(v.w); a7 += bfhi(v.w);
  }
  #pragma unroll
  for (int m = 16; m <= 32; m <<= 1) {
    a0 += __shfl_xor(a0, m, 64); a1 += __shfl_xor(a1, m, 64);
    a2 += __shfl_xor(a2, m, 64); a3 += __shfl_xor(a3, m, 64);
    a4 += __shfl_xor(a4, m, 64); a5 += __shfl_xor(a5, m, 64);
    a6 += __shfl_xor(a6, m, 64); a7 += __shfl_xor(a7, m, 64);
  }
  if (r == 0) {
    float inv = 1.0f / fmaxf((float)(hi - lo), 1.0f);
    float4* o = (float4*)(gp + (size_t)g*128 + c*8);
    o[0] = (float4){a0*inv, a1*inv, a2*inv, a3*inv};
    o[1] = (float4){a4*inv, a5*inv, a6*inv, a7*inv};
  }
}

// ---- out = relu(g @ W_out + b_out), fp32 vector ----
__global__ __launch_bounds__(128) void k_out(const float* __restrict__ gp, const float* __restrict__ Wout,
                                             const float* __restrict__ bout, float* __restrict__ out, int G){
  __shared__ float sg[128];
  int g = blockIdx.x, c = threadIdx.x;
  sg[c] = gp[g*128 + c];
  __syncthreads();
  float a = 0.f;
  #pragma unroll
  for (int k = 0; k < 128; ++k) a = fmaf(sg[k], Wout[k*128 + c], a);
  out[g*128 + c] = fmaxf(a + bout[c], 0.f);
}

extern "C" void kernel_launch(void* const* d_in, const int* in_sizes, int n_in,
                              void* d_out, int out_size, void* d_ws, size_t ws_size,
                              hipStream_t stream){
  (void)n_in; (void)ws_size;
  const float* x       = (const float*)d_in[0];
  const int*   ei      = (const int*)d_in[1];
  const int*   batch   = (const int*)d_in[2];
  const float* W_in    = (const float*)d_in[4];
  const float* b_in    = (const float*)d_in[5];
  const float* W_convs = (const float*)d_in[6];
  const float* b_convs = (const float*)d_in[7];
  const float* W_out   = (const float*)d_in[8];
  const float* b_out   = (const float*)d_in[9];
  float* out = (float*)d_out;

  int N = in_sizes[0];        // 100000
  int E = in_sizes[1] / 2;    // 400000
  int G = out_size / HID;     // 2048

  char* p = (char*)d_ws;
  auto alloc = [&](size_t bytes) -> char* {
    char* r = p; p += (bytes + 255) & ~(size_t)255; return r;
  };
  unsigned* h      = (unsigned*)alloc((size_t)N * 64 * 4);   // [N][128] bf16
  unsigned* hw     = (unsigned*)alloc((size_t)N * 64 * 4);   // [N][128] bf16
  uint4*    wf     = (uint4*)   alloc(3 * 2048 * 16);        // frag-ordered W
  float*    dinv   = (float*)   alloc((size_t)N * 4);
  int*      cnt    = (int*)     alloc((size_t)N * 4);
  int*      rp     = (int*)     alloc((size_t)(N + 1) * 4);
  int*      cursor = (int*)     alloc((size_t)(N + 1) * 4);
  int2*     ew     = (int2*)    alloc((size_t)E * 8);        // {src, dinv[src]}
  float*    gp     = (float*)   alloc((size_t)G * HID * 4);
  int*      bsum   = (int*)     alloc(4096);

  const int* src  = ei;
  const int* dstp = ei + E;

  k_zero<<<(N/4 + 255) / 256, 256, 0, stream>>>(cnt, N);
  k_deg <<<(E + 255) / 256, 256, 0, stream>>>(dstp, cnt, E);
  int nb = (N + 1023) / 1024;
  k_scan1<<<nb, 1024, 0, stream>>>(cnt, rp, bsum, dinv, N);
  k_scan2<<<1, 128, 0, stream>>>(bsum, rp, nb, N);
  k_scan3<<<nb, 1024, 0, stream>>>(rp, cursor, bsum, N);
  k_fill<<<(E + 255) / 256, 256, 0, stream>>>(src, dstp, cursor, ew, dinv, E);
  k_prepw<<<24, 256, 0, stream>>>(W_convs, wf);

  int gb = (N + 127) / 128;
  k_gemm0<<<gb, 256, 0, stream>>>(x, W_in, b_in, wf, (unsigned short*)hw, N);
  k_agg  <<<(N + 3) / 4, 256, 0, stream>>>((const uint2*)hw, (uint2*)h, rp, ew, dinv, b_convs, N);
  for (int l = 1; l < 3; ++l) {
    k_gemm<<<gb, 256, 0, stream>>>((const unsigned short*)h, wf + l * 2048,
                                   (unsigned short*)hw, N);
    k_agg <<<(N + 3) / 4, 256, 0, stream>>>((const uint2*)hw, (uint2*)h, rp, ew, dinv,
                                            b_convs + l * HID, N);
  }

  k_pool<<<(G + 3) / 4, 256, 0, stream>>>((const uint4*)h, batch, gp, N, G);
  k_out <<<G, HID, 0, stream>>>(gp, W_out, b_out, out, G);
}

// Round 4
// 219.179 us; speedup vs baseline: 1.3734x; 1.1068x over previous
//
#include <hip/hip_runtime.h>

#define HID 128

typedef __attribute__((ext_vector_type(8))) short short8;
typedef __attribute__((ext_vector_type(4))) float floatx4;

__device__ __forceinline__ float bflo(unsigned u){ return __uint_as_float(u << 16); }
__device__ __forceinline__ float bfhi(unsigned u){ return __uint_as_float(u & 0xffff0000u); }
__device__ __forceinline__ unsigned packbf2(float a, float b){
  unsigned ua = __float_as_uint(a), ub = __float_as_uint(b);
  ua = (ua + 0x7fffu + ((ua >> 16) & 1u)) >> 16;
  ub = (ub + 0x7fffu + ((ub >> 16) & 1u)) >> 16;
  return (ua & 0xffffu) | ((ub & 0xffffu) << 16);
}
__device__ __forceinline__ short8 as_s8(uint4 v){ short8 r; __builtin_memcpy(&r, &v, 16); return r; }

// ---- zero cnt ----
__global__ __launch_bounds__(256) void k_zero(int* __restrict__ p, int n){
  int i = blockIdx.x*256 + threadIdx.x;
  int n4 = n >> 2;
  if (i < n4) ((int4*)p)[i] = (int4){0,0,0,0};
  if (i == 0) for (int r = n4*4; r < n; ++r) p[r] = 0;
}

// ---- degree histogram ----
__global__ __launch_bounds__(256) void k_deg(const int* __restrict__ dst, int* __restrict__ cnt, int E){
  int e = blockIdx.x*256 + threadIdx.x;
  if (e < E) atomicAdd(&cnt[dst[e]], 1);
}

// ---- hierarchical exclusive scan (CSR row_ptr) + dinv ----
__global__ __launch_bounds__(1024) void k_scan1(const int* __restrict__ cnt, int* __restrict__ rp,
                                                int* __restrict__ bsum, float* __restrict__ dinv, int N){
  __shared__ int s[1024];
  int t = threadIdx.x;
  int i = blockIdx.x*1024 + t;
  int v = (i < N) ? cnt[i] : 0;
  s[t] = v;
  __syncthreads();
  for (int d = 1; d < 1024; d <<= 1) {
    int add = (t >= d) ? s[t - d] : 0;
    __syncthreads();
    s[t] += add;
    __syncthreads();
  }
  if (i < N) {
    rp[i] = s[t] - v;          // exclusive within chunk
    dinv[i] = 1.0f / sqrtf((float)v + 1.0f);
  }
  if (t == 1023) bsum[blockIdx.x] = s[1023];
}

// ---- scan3 with folded block-sum scan (each block scans bsum redundantly) ----
__global__ __launch_bounds__(1024) void k_scan3(int* __restrict__ rp, int* __restrict__ cursor,
                                                const int* __restrict__ bsum, int nb, int N){
  __shared__ int s[128];
  int t = threadIdx.x;
  if (t < 128) s[t] = (t < nb) ? bsum[t] : 0;
  __syncthreads();
  for (int d = 1; d < 128; d <<= 1) {
    int add = 0;
    if (t < 128 && t >= d) add = s[t - d];
    __syncthreads();
    if (t < 128) s[t] += add;
    __syncthreads();
  }
  // s[b] = inclusive sum of bsum[0..b]
  int base = (blockIdx.x > 0) ? s[blockIdx.x - 1] : 0;
  int i = blockIdx.x*1024 + t;
  if (i < N) {
    int v = rp[i] + base;
    rp[i] = v;
    cursor[i] = v;
  }
  if (blockIdx.x == 0 && t == 0) rp[N] = s[nb - 1];   // == E
}

// ---- CSR fill (by dst): packed {src, dinv[src]} per edge ----
__global__ __launch_bounds__(256) void k_fill(const int* __restrict__ src, const int* __restrict__ dst,
                                              int* __restrict__ cursor, int2* __restrict__ ew,
                                              const float* __restrict__ dinv, int E){
  int e = blockIdx.x*256 + threadIdx.x;
  if (e < E){
    int d = dst[e], s = src[e];
    int pos = atomicAdd(&cursor[d], 1);
    int2 pk; pk.x = s; pk.y = __float_as_int(dinv[s]);
    ew[pos] = pk;
  }
}

// ---- W_convs -> bf16 MFMA A-fragment order ----
__global__ __launch_bounds__(256) void k_prepw(const float* __restrict__ Wc, uint4* __restrict__ wf){
  int t = blockIdx.x*256 + threadIdx.x;
  if (t >= 3*2048) return;
  int l = t >> 11, r = t & 2047;
  int kt = r >> 9, ct = (r >> 6) & 7, lane = r & 63;
  int kbase = kt*32 + (lane >> 4)*8;
  int m = ct*16 + (lane & 15);
  const float* Wl = Wc + l*16384;
  float v[8];
  #pragma unroll
  for (int i = 0; i < 8; ++i) v[i] = Wl[(kbase + i)*128 + m];
  uint4 o;
  o.x = packbf2(v[0], v[1]);
  o.y = packbf2(v[2], v[3]);
  o.z = packbf2(v[4], v[5]);
  o.w = packbf2(v[6], v[7]);
  wf[t] = o;
}

// ---- layer-0 GEMM with fused h0 = relu(x*W_in + b_in) ----
__global__ __launch_bounds__(256) void k_gemm0(const float* __restrict__ x,
                                               const float* __restrict__ Win,
                                               const float* __restrict__ bin,
                                               const uint4* __restrict__ wf,
                                               unsigned short* __restrict__ hwout, int N){
  __shared__ uint4 lwf[2048];
  __shared__ float sw[128], sb[128];
  int t = threadIdx.x;
  #pragma unroll
  for (int j = 0; j < 8; ++j) lwf[t + j*256] = wf[t + j*256];
  if (t < 128) { sw[t] = Win[t]; sb[t] = bin[t]; }
  __syncthreads();
  int lane = t & 63, w = t >> 6;
  int rb = blockIdx.x*128 + w*32;
  int nrow0 = rb + (lane & 15);
  int nrow1 = nrow0 + 16;
  float xv0 = x[nrow0 < N ? nrow0 : N - 1];
  float xv1 = x[nrow1 < N ? nrow1 : N - 1];
  floatx4 acc0[8], acc1[8];
  #pragma unroll
  for (int c = 0; c < 8; ++c) { acc0[c] = (floatx4){0.f,0.f,0.f,0.f}; acc1[c] = (floatx4){0.f,0.f,0.f,0.f}; }
  #pragma unroll
  for (int kt = 0; kt < 4; ++kt) {
    int k0 = kt*32 + (lane >> 4)*8;
    float hv0[8], hv1[8];
    #pragma unroll
    for (int i = 0; i < 8; ++i) {
      float wv = sw[k0 + i], bv = sb[k0 + i];
      hv0[i] = fmaxf(fmaf(xv0, wv, bv), 0.f);
      hv1[i] = fmaxf(fmaf(xv1, wv, bv), 0.f);
    }
    uint4 p0, p1;
    p0.x = packbf2(hv0[0], hv0[1]); p0.y = packbf2(hv0[2], hv0[3]);
    p0.z = packbf2(hv0[4], hv0[5]); p0.w = packbf2(hv0[6], hv0[7]);
    p1.x = packbf2(hv1[0], hv1[1]); p1.y = packbf2(hv1[2], hv1[3]);
    p1.z = packbf2(hv1[4], hv1[5]); p1.w = packbf2(hv1[6], hv1[7]);
    short8 hf0 = as_s8(p0), hf1 = as_s8(p1);
    #pragma unroll
    for (int c = 0; c < 8; ++c) {
      short8 af = as_s8(lwf[(kt*8 + c)*64 + lane]);
      acc0[c] = __builtin_amdgcn_mfma_f32_16x16x32_bf16(af, hf0, acc0[c], 0, 0, 0);
      acc1[c] = __builtin_amdgcn_mfma_f32_16x16x32_bf16(af, hf1, acc1[c], 0, 0, 0);
    }
  }
  if (nrow0 < N) {
    unsigned short* op = hwout + (size_t)nrow0*128 + (lane >> 4)*4;
    #pragma unroll
    for (int c = 0; c < 8; ++c) {
      uint2 pk;
      pk.x = packbf2(acc0[c][0], acc0[c][1]);
      pk.y = packbf2(acc0[c][2], acc0[c][3]);
      *(uint2*)(op + c*16) = pk;
    }
  }
  if (nrow1 < N) {
    unsigned short* op = hwout + (size_t)nrow1*128 + (lane >> 4)*4;
    #pragma unroll
    for (int c = 0; c < 8; ++c) {
      uint2 pk;
      pk.x = packbf2(acc1[c][0], acc1[c][1]);
      pk.y = packbf2(acc1[c][2], acc1[c][3]);
      *(uint2*)(op + c*16) = pk;
    }
  }
}

// ---- hw = h @ W (bf16 MFMA), 2 row-tiles per wave ----
__global__ __launch_bounds__(256) void k_gemm(const unsigned short* __restrict__ hin,
                                              const uint4* __restrict__ wf,
                                              unsigned short* __restrict__ hwout, int N){
  __shared__ uint4 lwf[2048];
  int t = threadIdx.x;
  #pragma unroll
  for (int j = 0; j < 8; ++j) lwf[t + j*256] = wf[t + j*256];
  __syncthreads();
  int lane = t & 63, w = t >> 6;
  int rb = blockIdx.x*128 + w*32;
  int nrow0 = rb + (lane & 15);
  int nrow1 = nrow0 + 16;
  int nc0 = nrow0 < N ? nrow0 : N - 1;
  int nc1 = nrow1 < N ? nrow1 : N - 1;
  const uint4* hp0 = (const uint4*)(hin + (size_t)nc0*128 + (lane >> 4)*8);
  const uint4* hp1 = (const uint4*)(hin + (size_t)nc1*128 + (lane >> 4)*8);
  floatx4 acc0[8], acc1[8];
  #pragma unroll
  for (int c = 0; c < 8; ++c) { acc0[c] = (floatx4){0.f,0.f,0.f,0.f}; acc1[c] = (floatx4){0.f,0.f,0.f,0.f}; }
  #pragma unroll
  for (int kt = 0; kt < 4; ++kt) {
    short8 hf0 = as_s8(hp0[kt*4]);
    short8 hf1 = as_s8(hp1[kt*4]);
    #pragma unroll
    for (int c = 0; c < 8; ++c) {
      short8 af = as_s8(lwf[(kt*8 + c)*64 + lane]);
      acc0[c] = __builtin_amdgcn_mfma_f32_16x16x32_bf16(af, hf0, acc0[c], 0, 0, 0);
      acc1[c] = __builtin_amdgcn_mfma_f32_16x16x32_bf16(af, hf1, acc1[c], 0, 0, 0);
    }
  }
  if (nrow0 < N) {
    unsigned short* op = hwout + (size_t)nrow0*128 + (lane >> 4)*4;
    #pragma unroll
    for (int c = 0; c < 8; ++c) {
      uint2 pk;
      pk.x = packbf2(acc0[c][0], acc0[c][1]);
      pk.y = packbf2(acc0[c][2], acc0[c][3]);
      *(uint2*)(op + c*16) = pk;
    }
  }
  if (nrow1 < N) {
    unsigned short* op = hwout + (size_t)nrow1*128 + (lane >> 4)*4;
    #pragma unroll
    for (int c = 0; c < 8; ++c) {
      uint2 pk;
      pk.x = packbf2(acc1[c][0], acc1[c][1]);
      pk.y = packbf2(acc1[c][2], acc1[c][3]);
      *(uint2*)(op + c*16) = pk;
    }
  }
}

// ---- aggregation: one 32-lane half-wave per node, 4ch per lane.
// No cross-lane reduce; 4 gathers in flight per node, 8 per wave. ----
__global__ __launch_bounds__(256) void k_agg(const uint2* __restrict__ hw2, uint2* __restrict__ h2,
                                             const int* __restrict__ rp, const int2* __restrict__ ew,
                                             const float* __restrict__ dinv,
                                             const float* __restrict__ bias, int N){
  int node = (blockIdx.x * blockDim.x + threadIdx.x) >> 5;
  int c = threadIdx.x & 31;
  if (node >= N) return;
  float dn = dinv[node];
  size_t rbase = (size_t)node * 32;
  uint2 su = hw2[rbase + c];                       // self row slice
  float a0 = dn * bflo(su.x), a1 = dn * bfhi(su.x);
  float a2 = dn * bflo(su.y), a3 = dn * bfhi(su.y);
  int e0 = rp[node], e1 = rp[node + 1];
  int last = e1 - 1;
  for (int e = e0; e < e1; e += 4) {
    int i1 = e + 1 <= last ? e + 1 : last;
    int i2 = e + 2 <= last ? e + 2 : last;
    int i3 = e + 3 <= last ? e + 3 : last;
    int2 p0 = ew[e], p1 = ew[i1], p2 = ew[i2], p3 = ew[i3];
    float w0 = __int_as_float(p0.y);
    float w1 = e + 1 <= last ? __int_as_float(p1.y) : 0.f;
    float w2 = e + 2 <= last ? __int_as_float(p2.y) : 0.f;
    float w3 = e + 3 <= last ? __int_as_float(p3.y) : 0.f;
    uint2 v0 = hw2[(size_t)p0.x * 32 + c];
    uint2 v1 = hw2[(size_t)p1.x * 32 + c];
    uint2 v2 = hw2[(size_t)p2.x * 32 + c];
    uint2 v3 = hw2[(size_t)p3.x * 32 + c];
    a0 = fmaf(w0, bflo(v0.x), a0); a1 = fmaf(w0, bfhi(v0.x), a1);
    a2 = fmaf(w0, bflo(v0.y), a2); a3 = fmaf(w0, bfhi(v0.y), a3);
    a0 = fmaf(w1, bflo(v1.x), a0); a1 = fmaf(w1, bfhi(v1.x), a1);
    a2 = fmaf(w1, bflo(v1.y), a2); a3 = fmaf(w1, bfhi(v1.y), a3);
    a0 = fmaf(w2, bflo(v2.x), a0); a1 = fmaf(w2, bfhi(v2.x), a1);
    a2 = fmaf(w2, bflo(v2.y), a2); a3 = fmaf(w2, bfhi(v2.y), a3);
    a0 = fmaf(w3, bflo(v3.x), a0); a1 = fmaf(w3, bfhi(v3.x), a1);
    a2 = fmaf(w3, bflo(v3.y), a2); a3 = fmaf(w3, bfhi(v3.y), a3);
  }
  float4 bv = *(const float4*)(bias + c*4);
  float r0 = fmaxf(fmaf(dn, a0, bv.x), 0.f);
  float r1 = fmaxf(fmaf(dn, a1, bv.y), 0.f);
  float r2 = fmaxf(fmaf(dn, a2, bv.z), 0.f);
  float r3 = fmaxf(fmaf(dn, a3, bv.w), 0.f);
  uint2 o;
  o.x = packbf2(r0, r1);
  o.y = packbf2(r2, r3);
  h2[rbase + c] = o;
}

// ---- global mean pool; 4 graphs/block, one wave per graph ----
__global__ __launch_bounds__(256) void k_pool(const uint4* __restrict__ h4, const int* __restrict__ batch,
                                              float* __restrict__ gp, int N, int G){
  int g = blockIdx.x * 4 + (threadIdx.x >> 6);
  int lane = threadIdx.x & 63;
  if (g >= G) return;
  int lo, hi;
  { int a = 0, b = N; while (a < b) { int m = (a + b) >> 1; if (batch[m] < g) a = m + 1; else b = m; } lo = a; }
  { int a = lo, b = N; while (a < b) { int m = (a + b) >> 1; if (batch[m] < g + 1) a = m + 1; else b = m; } hi = a; }
  int r = lane >> 4;
  int c = lane & 15;
  float a0=0.f,a1=0.f,a2=0.f,a3=0.f,a4=0.f,a5=0.f,a6=0.f,a7=0.f;
  for (int n = lo + r; n < hi; n += 4) {
    uint4 v = h4[(size_t)n*16 + c];
    a0 += bflo(v.x); a1 += bfhi(v.x);
    a2 += bflo(v.y); a3 += bfhi(v.y);
    a4 += bflo(v.z); a5 += bfhi(v.z);
    a6 += bflo(v.w); a7 += bfhi(v.w);
  }
  #pragma unroll
  for (int m = 16; m <= 32; m <<= 1) {
    a0 += __shfl_xor(a0, m, 64); a1 += __shfl_xor(a1, m, 64);
    a2 += __shfl_xor(a2, m, 64); a3 += __shfl_xor(a3, m, 64);
    a4 += __shfl_xor(a4, m, 64); a5 += __shfl_xor(a5, m, 64);
    a6 += __shfl_xor(a6, m, 64); a7 += __shfl_xor(a7, m, 64);
  }
  if (r == 0) {
    float inv = 1.0f / fmaxf((float)(hi - lo), 1.0f);
    float4* o = (float4*)(gp + (size_t)g*128 + c*8);
    o[0] = (float4){a0*inv, a1*inv, a2*inv, a3*inv};
    o[1] = (float4){a4*inv, a5*inv, a6*inv, a7*inv};
  }
}

// ---- out = relu(g @ W_out + b_out), fp32 vector ----
__global__ __launch_bounds__(128) void k_out(const float* __restrict__ gp, const float* __restrict__ Wout,
                                             const float* __restrict__ bout, float* __restrict__ out, int G){
  __shared__ float sg[128];
  int g = blockIdx.x, c = threadIdx.x;
  sg[c] = gp[g*128 + c];
  __syncthreads();
  float a = 0.f;
  #pragma unroll
  for (int k = 0; k < 128; ++k) a = fmaf(sg[k], Wout[k*128 + c], a);
  out[g*128 + c] = fmaxf(a + bout[c], 0.f);
}

extern "C" void kernel_launch(void* const* d_in, const int* in_sizes, int n_in,
                              void* d_out, int out_size, void* d_ws, size_t ws_size,
                              hipStream_t stream){
  (void)n_in; (void)ws_size;
  const float* x       = (const float*)d_in[0];
  const int*   ei      = (const int*)d_in[1];
  const int*   batch   = (const int*)d_in[2];
  const float* W_in    = (const float*)d_in[4];
  const float* b_in    = (const float*)d_in[5];
  const float* W_convs = (const float*)d_in[6];
  const float* b_convs = (const float*)d_in[7];
  const float* W_out   = (const float*)d_in[8];
  const float* b_out   = (const float*)d_in[9];
  float* out = (float*)d_out;

  int N = in_sizes[0];        // 100000
  int E = in_sizes[1] / 2;    // 400000
  int G = out_size / HID;     // 2048

  char* p = (char*)d_ws;
  auto alloc = [&](size_t bytes) -> char* {
    char* r = p; p += (bytes + 255) & ~(size_t)255; return r;
  };
  unsigned* h      = (unsigned*)alloc((size_t)N * 64 * 4);   // [N][128] bf16
  unsigned* hw     = (unsigned*)alloc((size_t)N * 64 * 4);   // [N][128] bf16
  uint4*    wf     = (uint4*)   alloc(3 * 2048 * 16);        // frag-ordered W
  float*    dinv   = (float*)   alloc((size_t)N * 4);
  int*      cnt    = (int*)     alloc((size_t)N * 4);
  int*      rp     = (int*)     alloc((size_t)(N + 1) * 4);
  int*      cursor = (int*)     alloc((size_t)(N + 1) * 4);
  int2*     ew     = (int2*)    alloc((size_t)E * 8);        // {src, dinv[src]}
  float*    gp     = (float*)   alloc((size_t)G * HID * 4);
  int*      bsum   = (int*)     alloc(4096);

  const int* src  = ei;
  const int* dstp = ei + E;

  k_zero<<<(N/4 + 255) / 256, 256, 0, stream>>>(cnt, N);
  k_deg <<<(E + 255) / 256, 256, 0, stream>>>(dstp, cnt, E);
  int nb = (N + 1023) / 1024;
  k_scan1<<<nb, 1024, 0, stream>>>(cnt, rp, bsum, dinv, N);
  k_scan3<<<nb, 1024, 0, stream>>>(rp, cursor, bsum, nb, N);
  k_fill<<<(E + 255) / 256, 256, 0, stream>>>(src, dstp, cursor, ew, dinv, E);
  k_prepw<<<24, 256, 0, stream>>>(W_convs, wf);

  int gb = (N + 127) / 128;
  k_gemm0<<<gb, 256, 0, stream>>>(x, W_in, b_in, wf, (unsigned short*)hw, N);
  k_agg  <<<(N + 7) / 8, 256, 0, stream>>>((const uint2*)hw, (uint2*)h, rp, ew, dinv, b_convs, N);
  for (int l = 1; l < 3; ++l) {
    k_gemm<<<gb, 256, 0, stream>>>((const unsigned short*)h, wf + l * 2048,
                                   (unsigned short*)hw, N);
    k_agg <<<(N + 7) / 8, 256, 0, stream>>>((const uint2*)hw, (uint2*)h, rp, ew, dinv,
                                            b_convs + l * HID, N);
  }

  k_pool<<<(G + 3) / 4, 256, 0, stream>>>((const uint4*)h, batch, gp, N, G);
  k_out <<<G, HID, 0, stream>>>(gp, W_out, b_out, out, G);
}